// Round 8
// baseline (259.596 us; speedup 1.0000x reference)
//
#include <hip/hip_runtime.h>

#define T_TOK 2048
#define DIM   512
#define MOE   256
#define NE    64
#define NG    8
#define TOPKG 4
#define TOPK  8
#define CAP   1024
#define MOE_SCALE 2.5f

typedef float f32x4 __attribute__((ext_vector_type(4)));
typedef short s16x8 __attribute__((ext_vector_type(8)));

__device__ __forceinline__ unsigned short f2bf(float f) {
    unsigned u = __builtin_bit_cast(unsigned, f);
    unsigned r = (u + 0x7fffu + ((u >> 16) & 1u)) >> 16;
    return (unsigned short)r;
}
__device__ __forceinline__ unsigned pk2(float lo, float hi) {
    return (unsigned)f2bf(lo) | ((unsigned)f2bf(hi) << 16);
}

// inline 64-lane exclusive scan of per-expert tile counts
__device__ __forceinline__ void tile_scan(const int* __restrict__ counts, int lane,
                                          int e, int& G0, int& ne, int& nt)
{
    int cl = min(counts[lane], CAP);
    int ntl = (cl + 31) >> 5;
    int v = ntl;
#pragma unroll
    for (int d = 1; d < 64; d <<= 1) {
        int o = __shfl_up(v, d);
        if (lane >= d) v += o;
    }
    G0 = __shfl(v - ntl, e);
    ne = __shfl(cl, e);
    nt = __shfl(ntl, e);
}

// ---------------- gw transpose ------------------------------------------------
__global__ __launch_bounds__(256) void gwt_k(const float* __restrict__ gw,
                                             float* __restrict__ gwT)
{
    int idx = blockIdx.x * 256 + threadIdx.x;
    int e = idx >> 9, k = idx & 511;
    gwT[(size_t)(k >> 2) * 256 + e * 4 + (k & 3)] = gw[idx];
}

// ---------------- Fused gating + x->bf16 --------------------------------------
__global__ __launch_bounds__(256) void gate_fused_k(const float* __restrict__ x,
                                                    const float* __restrict__ gwT,
                                                    const float* __restrict__ gb,
                                                    int* __restrict__ counts,
                                                    int* __restrict__ etok,
                                                    float* __restrict__ wt_of,
                                                    short* __restrict__ xb)
{
    __shared__ float xs[4][512];
    __shared__ float ps[4][4][64];      // producer wave, token, expert
    int w = threadIdx.x >> 6, lane = threadIdx.x & 63;
    int t = blockIdx.x * 4 + w;

    {
        const float4* xr = (const float4*)(x + (size_t)t * DIM);
        float4 v0 = xr[lane * 2], v1 = xr[lane * 2 + 1];
        *(float4*)&xs[w][lane * 8]     = v0;
        *(float4*)&xs[w][lane * 8 + 4] = v1;
        short o[8];
        o[0] = (short)f2bf(v0.x); o[1] = (short)f2bf(v0.y);
        o[2] = (short)f2bf(v0.z); o[3] = (short)f2bf(v0.w);
        o[4] = (short)f2bf(v1.x); o[5] = (short)f2bf(v1.y);
        o[6] = (short)f2bf(v1.z); o[7] = (short)f2bf(v1.w);
        *(s16x8*)(xb + (size_t)t * DIM + lane * 8) = *(const s16x8*)o;
    }
    __syncthreads();

    // wave w covers k4 in [w*32, w*32+32) for ALL 4 tokens of the block
    const f32x4* gt = (const f32x4*)gwT;
    float a0 = 0.f, a1 = 0.f, a2 = 0.f, a3 = 0.f;
    int kb = w * 32;
#pragma unroll 8
    for (int k4 = 0; k4 < 32; ++k4) {
        f32x4 g  = gt[(size_t)(kb + k4) * 64 + lane];
        f32x4 x0 = *(const f32x4*)&xs[0][(kb + k4) * 4];
        f32x4 x1 = *(const f32x4*)&xs[1][(kb + k4) * 4];
        f32x4 x2 = *(const f32x4*)&xs[2][(kb + k4) * 4];
        f32x4 x3 = *(const f32x4*)&xs[3][(kb + k4) * 4];
        a0 += g.x * x0.x + g.y * x0.y + g.z * x0.z + g.w * x0.w;
        a1 += g.x * x1.x + g.y * x1.y + g.z * x1.z + g.w * x1.w;
        a2 += g.x * x2.x + g.y * x2.y + g.z * x2.z + g.w * x2.w;
        a3 += g.x * x3.x + g.y * x3.y + g.z * x3.z + g.w * x3.w;
    }
    ps[w][0][lane] = a0; ps[w][1][lane] = a1;
    ps[w][2][lane] = a2; ps[w][3][lane] = a3;
    __syncthreads();
    float acc = ps[0][w][lane] + ps[1][w][lane] + ps[2][w][lane] + ps[3][w][lane];

    float sc = 1.f / (1.f + __expf(-acc));
    float s  = sc + gb[lane];

    float m1 = s, m2 = -1e30f;
#pragma unroll
    for (int d = 1; d < 8; d <<= 1) {
        float o1 = __shfl_xor(m1, d);
        float o2 = __shfl_xor(m2, d);
        float n1 = fmaxf(m1, o1);
        float n2 = fmaxf(fminf(m1, o1), fmaxf(m2, o2));
        m1 = n1; m2 = n2;
    }
    float gv = m1 + m2;

    bool gkeep = false;
#pragma unroll
    for (int it = 0; it < TOPKG; ++it) {
        float m = gv;
#pragma unroll
        for (int d = 1; d < 64; d <<= 1) m = fmaxf(m, __shfl_xor(m, d));
        unsigned long long mask = __ballot(gv == m);
        int ldr = __ffsll(mask) - 1;
        if ((lane >> 3) == (ldr >> 3)) { gkeep = true; gv = -2e30f; }
    }
    float sv = gkeep ? s : -1e30f;

    float wsum = 0.f;
    int my_e = 0; float my_w = 0.f;
#pragma unroll
    for (int k = 0; k < TOPK; ++k) {
        float m = sv;
#pragma unroll
        for (int d = 1; d < 64; d <<= 1) m = fmaxf(m, __shfl_xor(m, d));
        unsigned long long mask = __ballot(sv == m);
        int l = __ffsll(mask) - 1;
        float wk = __shfl(sc, l);
        wsum += wk;
        if (lane == k) { my_e = l; my_w = wk; }
        if (lane == l) sv = -2e30f;
    }
    float scale = MOE_SCALE / wsum;
    if (lane < TOPK) {
        int p = atomicAdd(&counts[my_e], 1);
        int rid = t * TOPK + lane;
        bool ok = (p < CAP);
        if (ok) etok[my_e * CAP + p] = rid;
        wt_of[rid] = ok ? my_w * scale : 0.f;
    }
}

// ---------------- Dispatch: gather tokens into per-expert frag-ordered xg -----
__global__ __launch_bounds__(256) void dispatch_k(const short* __restrict__ xb,
                                                  const int* __restrict__ counts,
                                                  const int* __restrict__ etok,
                                                  short* __restrict__ xg)
{
    int e = blockIdx.x & 63, sub = blockIdx.x >> 6;
    int w = threadIdx.x >> 6, lane = threadIdx.x & 63;

    int G0, ne, nt;
    tile_scan(counts, lane, e, G0, ne, nt);
    int rows = nt * 32;
    const int* el = etok + e * CAP;

    int kt = lane >> 2, qq = lane & 3;
    for (int p = sub * 4 + w; p < rows; p += 32) {   // wave per row, balanced
        s16x8 v = {0, 0, 0, 0, 0, 0, 0, 0};
        if (p < ne) {
            int tok = el[p] >> 3;
            v = *(const s16x8*)(xb + (size_t)tok * DIM + lane * 8);
        }
        int st = (p >> 4) & 1, m = p & 15;
        size_t off = ((((size_t)(G0 + (p >> 5)) * 16 + kt) * 2 + st) * 64
                      + (qq * 16 + m)) * 8;
        *(s16x8*)(xg + off) = v;
    }
}

// ---------------- K1: h = silu(X@W1)*(X@W3) -----------------------------------
// The untested quadrant: (256,2) cap KEPT (2 blocks/CU — R7 showed uncapping
// halves occupancy and stalls the latency-bound stage) AND no spill, by
// shrinking the live set: prefetch depth 4->2 (A is linear L2-resident xg
// since R5; 2-deep issue distance ~200+ cy covers L2 latency). Live set
// ~= acc32 + pa16 + b16 + misc ~30 < 128 -> no spill at the cap.
__global__ __launch_bounds__(256, 2) void gemm1_k(const short* __restrict__ xg,
                                                  const float* __restrict__ w1,
                                                  const float* __restrict__ w3,
                                                  const int* __restrict__ counts,
                                                  short* __restrict__ hgf)
{
    __shared__ short Bl[2][16][2][64][8];    // mat, kt, cgrp, flane, j = 64 KB
    __shared__ short Ct[4][2][16][24];       // wave, sub, row, col(+pad) = 6 KB

    int e  = blockIdx.x & 63, cg = blockIdx.x >> 6;   // cg 0..7 -> 32-col slice
    int n0 = cg * 32;
    int tid = threadIdx.x;
    int w = tid >> 6, lane = tid & 63;
    int q = lane >> 4, m16 = lane & 15;

    int G0, ne, nt;
    tile_scan(counts, lane, e, G0, ne, nt);
    (void)ne;

    const float* W1e = w1 + (size_t)e * DIM * MOE + n0;
    const float* W3e = w3 + (size_t)e * DIM * MOE + n0;
#pragma unroll 4
    for (int it = 0; it < 16; ++it) {
        int idx = it * 256 + tid;
        int mat = idx >> 11;
        int rem = idx & 2047;
        int r2  = rem >> 3;              // row pair 0..255
        int cq  = (rem & 7) * 4;         // col 0..28 step 4
        int k   = r2 * 2;
        int kt = k >> 5, qf = (k >> 3) & 3, j0 = k & 7;
        int cgrp = cq >> 4, c15 = cq & 15;
        const float* p = (mat ? W3e : W1e) + (size_t)k * MOE + cq;
        f32x4 lo = __builtin_nontemporal_load((const f32x4*)p);
        f32x4 hi = __builtin_nontemporal_load((const f32x4*)(p + MOE));
        unsigned* b = (unsigned*)&Bl[mat][kt][cgrp][qf * 16 + c15][j0];
        b[0]  = pk2(lo.x, hi.x);
        b[4]  = pk2(lo.y, hi.y);
        b[8]  = pk2(lo.z, hi.z);
        b[12] = pk2(lo.w, hi.w);
    }
    __syncthreads();

    for (int T = w; T < nt; T += 4) {
        const short* A = xg + (size_t)(G0 + T) * 16384 + lane * 8;

        f32x4 acc[2][2][2];   // [sub][mat][cgrp]
#pragma unroll
        for (int i = 0; i < 2; ++i)
#pragma unroll
            for (int j = 0; j < 2; ++j)
#pragma unroll
                for (int c = 0; c < 2; ++c) acc[i][j][c] = (f32x4)0.f;

        // 2-deep rolling A-prefetch (static indices after unroll; fits 128V)
        s16x8 pa0[2], pa1[2];
#pragma unroll
        for (int i = 0; i < 2; ++i) {
            pa0[i] = *(const s16x8*)(A + (i * 2 + 0) * 512);
            pa1[i] = *(const s16x8*)(A + (i * 2 + 1) * 512);
        }
#pragma unroll
        for (int kt = 0; kt < 16; ++kt) {
            s16x8 a0 = pa0[kt & 1], a1 = pa1[kt & 1];
            if (kt < 14) {
                pa0[kt & 1] = *(const s16x8*)(A + ((kt + 2) * 2 + 0) * 512);
                pa1[kt & 1] = *(const s16x8*)(A + ((kt + 2) * 2 + 1) * 512);
            }
            s16x8 b10 = *(const s16x8*)&Bl[0][kt][0][lane][0];
            s16x8 b11 = *(const s16x8*)&Bl[0][kt][1][lane][0];
            s16x8 b30 = *(const s16x8*)&Bl[1][kt][0][lane][0];
            s16x8 b31 = *(const s16x8*)&Bl[1][kt][1][lane][0];
            acc[0][0][0] = __builtin_amdgcn_mfma_f32_16x16x32_bf16(a0, b10, acc[0][0][0], 0, 0, 0);
            acc[1][0][0] = __builtin_amdgcn_mfma_f32_16x16x32_bf16(a1, b10, acc[1][0][0], 0, 0, 0);
            acc[0][0][1] = __builtin_amdgcn_mfma_f32_16x16x32_bf16(a0, b11, acc[0][0][1], 0, 0, 0);
            acc[1][0][1] = __builtin_amdgcn_mfma_f32_16x16x32_bf16(a1, b11, acc[1][0][1], 0, 0, 0);
            acc[0][1][0] = __builtin_amdgcn_mfma_f32_16x16x32_bf16(a0, b30, acc[0][1][0], 0, 0, 0);
            acc[1][1][0] = __builtin_amdgcn_mfma_f32_16x16x32_bf16(a1, b30, acc[1][1][0], 0, 0, 0);
            acc[0][1][1] = __builtin_amdgcn_mfma_f32_16x16x32_bf16(a0, b31, acc[0][1][1], 0, 0, 0);
            acc[1][1][1] = __builtin_amdgcn_mfma_f32_16x16x32_bf16(a1, b31, acc[1][1][1], 0, 0, 0);
        }

        // epilogue: SwiGLU -> Ct transpose -> contiguous frag store, per cgrp
#pragma unroll
        for (int cgrp = 0; cgrp < 2; ++cgrp) {
#pragma unroll
            for (int sub = 0; sub < 2; ++sub)
#pragma unroll
                for (int r = 0; r < 4; ++r) {
                    float g = acc[sub][0][cgrp][r];
                    float u = acc[sub][1][cgrp][r];
                    float hv = g / (1.f + __expf(-g)) * u;
                    Ct[w][sub][q * 4 + r][m16] = (short)f2bf(hv);
                }
            int subr = q >> 1;
            s16x8 hv8 = *(const s16x8*)&Ct[w][subr][m16][(q & 1) * 8];
            size_t slot = ((size_t)(G0 + T) * 8 + cg) * 2 + subr;
            *(s16x8*)(hgf + slot * 512 + (cgrp * 2 + (q & 1)) * 128 + m16 * 8) = hv8;
        }
    }
}

// ---------------- K2: y = H@W2 ------------------------------------------------
// Same fix: (256,3) kept, prefetch depth 2 (A = linear L2-resident hgf).
__global__ __launch_bounds__(256, 3) void gemm2_k(const short* __restrict__ hgf,
                                                  const float* __restrict__ w2,
                                                  const int* __restrict__ counts,
                                                  const int* __restrict__ etok,
                                                  short* __restrict__ ybuf)
{
    __shared__ short Bl[4][8][64][8];   // 16-col slice, kt2, flane, j = 32 KB

    int e  = blockIdx.x & 63, cg = blockIdx.x >> 6;   // cg 0..7 -> 64-col slice
    int n0 = cg * 64;
    int tid = threadIdx.x;
    int w = tid >> 6, lane = tid & 63;
    int q = lane >> 4, m16 = lane & 15;

    int G0, ne, nt;
    tile_scan(counts, lane, e, G0, ne, nt);

    const float* W2e = w2 + (size_t)e * MOE * DIM + n0;
#pragma unroll 4
    for (int it = 0; it < 8; ++it) {
        int idx = it * 256 + tid;
        int r2  = idx >> 4;              // row pair 0..127
        int cq  = (idx & 15) * 4;        // col 0..60 step 4
        int k   = r2 * 2;
        int kt2 = k >> 5, qf = (k >> 3) & 3, j0 = k & 7;
        int s = cq >> 4, c15 = cq & 15;
        const float* p = W2e + (size_t)k * DIM + cq;
        f32x4 lo = __builtin_nontemporal_load((const f32x4*)p);
        f32x4 hi = __builtin_nontemporal_load((const f32x4*)(p + DIM));
        unsigned* b = (unsigned*)&Bl[s][kt2][qf * 16 + c15][j0];
        b[0]  = pk2(lo.x, hi.x);
        b[4]  = pk2(lo.y, hi.y);
        b[8]  = pk2(lo.z, hi.z);
        b[12] = pk2(lo.w, hi.w);
    }
    __syncthreads();

    const int* el = etok + e * CAP;

    for (int T = w; T < nt; T += 4) {
        const short* A = hgf + (size_t)(G0 + T) * 8192 + lane * 8;

        int erid[2][4];                  // hoisted: issues el loads early
#pragma unroll
        for (int sub = 0; sub < 2; ++sub)
#pragma unroll
            for (int r = 0; r < 4; ++r) {
                int row = T * 32 + sub * 16 + q * 4 + r;
                erid[sub][r] = row < ne ? el[row] : -1;
            }

        f32x4 acc[2][4];   // [sub][slice]
#pragma unroll
        for (int i = 0; i < 2; ++i)
#pragma unroll
            for (int j = 0; j < 4; ++j) acc[i][j] = (f32x4)0.f;

        s16x8 pa0[2], pa1[2];
#pragma unroll
        for (int i = 0; i < 2; ++i) {
            pa0[i] = *(const s16x8*)(A + (i * 2 + 0) * 512);
            pa1[i] = *(const s16x8*)(A + (i * 2 + 1) * 512);
        }
#pragma unroll
        for (int kt = 0; kt < 8; ++kt) {
            s16x8 a0 = pa0[kt & 1], a1 = pa1[kt & 1];
            if (kt < 6) {
                pa0[kt & 1] = *(const s16x8*)(A + ((kt + 2) * 2 + 0) * 512);
                pa1[kt & 1] = *(const s16x8*)(A + ((kt + 2) * 2 + 1) * 512);
            }
            s16x8 b0 = *(const s16x8*)&Bl[0][kt][lane][0];
            s16x8 b1 = *(const s16x8*)&Bl[1][kt][lane][0];
            s16x8 b2 = *(const s16x8*)&Bl[2][kt][lane][0];
            s16x8 b3 = *(const s16x8*)&Bl[3][kt][lane][0];
            acc[0][0] = __builtin_amdgcn_mfma_f32_16x16x32_bf16(a0, b0, acc[0][0], 0, 0, 0);
            acc[1][0] = __builtin_amdgcn_mfma_f32_16x16x32_bf16(a1, b0, acc[1][0], 0, 0, 0);
            acc[0][1] = __builtin_amdgcn_mfma_f32_16x16x32_bf16(a0, b1, acc[0][1], 0, 0, 0);
            acc[1][1] = __builtin_amdgcn_mfma_f32_16x16x32_bf16(a1, b1, acc[1][1], 0, 0, 0);
            acc[0][2] = __builtin_amdgcn_mfma_f32_16x16x32_bf16(a0, b2, acc[0][2], 0, 0, 0);
            acc[1][2] = __builtin_amdgcn_mfma_f32_16x16x32_bf16(a1, b2, acc[1][2], 0, 0, 0);
            acc[0][3] = __builtin_amdgcn_mfma_f32_16x16x32_bf16(a0, b3, acc[0][3], 0, 0, 0);
            acc[1][3] = __builtin_amdgcn_mfma_f32_16x16x32_bf16(a1, b3, acc[1][3], 0, 0, 0);
        }

#pragma unroll
        for (int sub = 0; sub < 2; ++sub)
#pragma unroll
            for (int s = 0; s < 4; ++s)
#pragma unroll
                for (int r = 0; r < 4; ++r) {
                    if (erid[sub][r] >= 0)
                        ybuf[(size_t)erid[sub][r] * DIM + n0 + s * 16 + m16] =
                            (short)f2bf(acc[sub][s][r]);
                }
    }
}

// ---------------- Combine -----------------------------------------------------
__global__ __launch_bounds__(256) void combine_k(const short* __restrict__ ybuf,
                                                 const float* __restrict__ wt_of,
                                                 float* __restrict__ out)
{
    int t = blockIdx.x;
    int tid = threadIdx.x;
    const int* yb = (const int*)ybuf;
    float sx = 0.f, sy = 0.f;
#pragma unroll
    for (int k = 0; k < TOPK; ++k) {
        float wk = wt_of[t * TOPK + k];
        int v = yb[(size_t)(t * TOPK + k) * (DIM / 2) + tid];
        float lo = __builtin_bit_cast(float, (unsigned)v << 16);
        float hi = __builtin_bit_cast(float, (unsigned)v & 0xffff0000u);
        sx += wk * lo;
        sy += wk * hi;
    }
    float2 o = {sx, sy};
    ((float2*)out)[(size_t)t * (DIM / 2) + tid] = o;
}

extern "C" void kernel_launch(void* const* d_in, const int* in_sizes, int n_in,
                              void* d_out, int out_size, void* d_ws, size_t ws_size,
                              hipStream_t stream)
{
    const float* x  = (const float*)d_in[0];
    const float* gw = (const float*)d_in[1];
    const float* gb = (const float*)d_in[2];
    const float* w1 = (const float*)d_in[3];
    const float* w3 = (const float*)d_in[4];
    const float* w2 = (const float*)d_in[5];

    char* ws = (char*)d_ws;
    short* xb    = (short*)(ws);                      //  2,097,152
    short* hgf   = (short*)(ws + 2097152);            //  9,437,184
    short* xg    = (short*)(ws + 11534336);           // 18,874,368
    short* ybuf  = (short*)(ws + 11534336);           // 16,777,216 — ALIASES xg
                                                      // (xg dead after gemm1;
                                                      //  ybuf born in gemm2)
    float* gwT   = (float*)(ws + 30408704);           //    131,072
    int*   etok  = (int*)  (ws + 30539776);           //    262,144
    float* wt_of = (float*)(ws + 30801920);           //     65,536
    int*   counts= (int*)  (ws + 30867456);           //        256

    hipMemsetAsync(counts, 0, NE * 4, stream);

    gwt_k<<<128, 256, 0, stream>>>(gw, gwT);
    gate_fused_k<<<T_TOK / 4, 256, 0, stream>>>(x, gwT, gb, counts, etok, wt_of, xb);
    dispatch_k<<<NE * 8, 256, 0, stream>>>(xb, counts, etok, xg);
    gemm1_k<<<NE * 8, 256, 0, stream>>>(xg, w1, w3, counts, hgf);
    gemm2_k<<<NE * 8, 256, 0, stream>>>(hgf, w2, counts, etok, ybuf);
    combine_k<<<T_TOK, 256, 0, stream>>>(ybuf, wt_of, (float*)d_out);
}

// Round 9
// 244.111 us; speedup vs baseline: 1.0634x; 1.0634x over previous
//
#include <hip/hip_runtime.h>

#define T_TOK 2048
#define DIM   512
#define MOE   256
#define NE    64
#define NG    8
#define TOPKG 4
#define TOPK  8
#define CAP   1024
#define MOE_SCALE 2.5f

typedef float f32x4 __attribute__((ext_vector_type(4)));
typedef short s16x8 __attribute__((ext_vector_type(8)));

__device__ __forceinline__ unsigned short f2bf(float f) {
    unsigned u = __builtin_bit_cast(unsigned, f);
    unsigned r = (u + 0x7fffu + ((u >> 16) & 1u)) >> 16;
    return (unsigned short)r;
}
__device__ __forceinline__ unsigned pk2(float lo, float hi) {
    return (unsigned)f2bf(lo) | ((unsigned)f2bf(hi) << 16);
}

// inline 64-lane exclusive scan of per-expert tile counts
__device__ __forceinline__ void tile_scan(const int* __restrict__ counts, int lane,
                                          int e, int& G0, int& ne, int& nt)
{
    int cl = min(counts[lane], CAP);
    int ntl = (cl + 31) >> 5;
    int v = ntl;
#pragma unroll
    for (int d = 1; d < 64; d <<= 1) {
        int o = __shfl_up(v, d);
        if (lane >= d) v += o;
    }
    G0 = __shfl(v - ntl, e);
    ne = __shfl(cl, e);
    nt = __shfl(ntl, e);
}

// ---------------- gw transpose ------------------------------------------------
__global__ __launch_bounds__(256) void gwt_k(const float* __restrict__ gw,
                                             float* __restrict__ gwT)
{
    int idx = blockIdx.x * 256 + threadIdx.x;
    int e = idx >> 9, k = idx & 511;
    gwT[(size_t)(k >> 2) * 256 + e * 4 + (k & 3)] = gw[idx];
}

// ---------------- Fused gating + x->bf16 --------------------------------------
__global__ __launch_bounds__(256) void gate_fused_k(const float* __restrict__ x,
                                                    const float* __restrict__ gwT,
                                                    const float* __restrict__ gb,
                                                    int* __restrict__ counts,
                                                    int* __restrict__ etok,
                                                    float* __restrict__ wt_of,
                                                    short* __restrict__ xb)
{
    __shared__ float xs[4][512];
    __shared__ float ps[4][4][64];      // producer wave, token, expert
    int w = threadIdx.x >> 6, lane = threadIdx.x & 63;
    int t = blockIdx.x * 4 + w;

    {
        const float4* xr = (const float4*)(x + (size_t)t * DIM);
        float4 v0 = xr[lane * 2], v1 = xr[lane * 2 + 1];
        *(float4*)&xs[w][lane * 8]     = v0;
        *(float4*)&xs[w][lane * 8 + 4] = v1;
        short o[8];
        o[0] = (short)f2bf(v0.x); o[1] = (short)f2bf(v0.y);
        o[2] = (short)f2bf(v0.z); o[3] = (short)f2bf(v0.w);
        o[4] = (short)f2bf(v1.x); o[5] = (short)f2bf(v1.y);
        o[6] = (short)f2bf(v1.z); o[7] = (short)f2bf(v1.w);
        *(s16x8*)(xb + (size_t)t * DIM + lane * 8) = *(const s16x8*)o;
    }
    __syncthreads();

    // wave w covers k4 in [w*32, w*32+32) for ALL 4 tokens of the block
    const f32x4* gt = (const f32x4*)gwT;
    float a0 = 0.f, a1 = 0.f, a2 = 0.f, a3 = 0.f;
    int kb = w * 32;
#pragma unroll 8
    for (int k4 = 0; k4 < 32; ++k4) {
        f32x4 g  = gt[(size_t)(kb + k4) * 64 + lane];
        f32x4 x0 = *(const f32x4*)&xs[0][(kb + k4) * 4];
        f32x4 x1 = *(const f32x4*)&xs[1][(kb + k4) * 4];
        f32x4 x2 = *(const f32x4*)&xs[2][(kb + k4) * 4];
        f32x4 x3 = *(const f32x4*)&xs[3][(kb + k4) * 4];
        a0 += g.x * x0.x + g.y * x0.y + g.z * x0.z + g.w * x0.w;
        a1 += g.x * x1.x + g.y * x1.y + g.z * x1.z + g.w * x1.w;
        a2 += g.x * x2.x + g.y * x2.y + g.z * x2.z + g.w * x2.w;
        a3 += g.x * x3.x + g.y * x3.y + g.z * x3.z + g.w * x3.w;
    }
    ps[w][0][lane] = a0; ps[w][1][lane] = a1;
    ps[w][2][lane] = a2; ps[w][3][lane] = a3;
    __syncthreads();
    float acc = ps[0][w][lane] + ps[1][w][lane] + ps[2][w][lane] + ps[3][w][lane];

    float sc = 1.f / (1.f + __expf(-acc));
    float s  = sc + gb[lane];

    float m1 = s, m2 = -1e30f;
#pragma unroll
    for (int d = 1; d < 8; d <<= 1) {
        float o1 = __shfl_xor(m1, d);
        float o2 = __shfl_xor(m2, d);
        float n1 = fmaxf(m1, o1);
        float n2 = fmaxf(fminf(m1, o1), fmaxf(m2, o2));
        m1 = n1; m2 = n2;
    }
    float gv = m1 + m2;

    bool gkeep = false;
#pragma unroll
    for (int it = 0; it < TOPKG; ++it) {
        float m = gv;
#pragma unroll
        for (int d = 1; d < 64; d <<= 1) m = fmaxf(m, __shfl_xor(m, d));
        unsigned long long mask = __ballot(gv == m);
        int ldr = __ffsll(mask) - 1;
        if ((lane >> 3) == (ldr >> 3)) { gkeep = true; gv = -2e30f; }
    }
    float sv = gkeep ? s : -1e30f;

    float wsum = 0.f;
    int my_e = 0; float my_w = 0.f;
#pragma unroll
    for (int k = 0; k < TOPK; ++k) {
        float m = sv;
#pragma unroll
        for (int d = 1; d < 64; d <<= 1) m = fmaxf(m, __shfl_xor(m, d));
        unsigned long long mask = __ballot(sv == m);
        int l = __ffsll(mask) - 1;
        float wk = __shfl(sc, l);
        wsum += wk;
        if (lane == k) { my_e = l; my_w = wk; }
        if (lane == l) sv = -2e30f;
    }
    float scale = MOE_SCALE / wsum;
    if (lane < TOPK) {
        int p = atomicAdd(&counts[my_e], 1);
        int rid = t * TOPK + lane;
        bool ok = (p < CAP);
        if (ok) etok[my_e * CAP + p] = rid;
        wt_of[rid] = ok ? my_w * scale : 0.f;
    }
}

// ---------------- Dispatch: gather tokens into per-expert frag-ordered xg -----
__global__ __launch_bounds__(256) void dispatch_k(const short* __restrict__ xb,
                                                  const int* __restrict__ counts,
                                                  const int* __restrict__ etok,
                                                  short* __restrict__ xg)
{
    int e = blockIdx.x & 63, sub = blockIdx.x >> 6;
    int w = threadIdx.x >> 6, lane = threadIdx.x & 63;

    int G0, ne, nt;
    tile_scan(counts, lane, e, G0, ne, nt);
    int rows = nt * 32;
    const int* el = etok + e * CAP;

    int kt = lane >> 2, qq = lane & 3;
    for (int p = sub * 4 + w; p < rows; p += 32) {   // wave per row, balanced
        s16x8 v = {0, 0, 0, 0, 0, 0, 0, 0};
        if (p < ne) {
            int tok = el[p] >> 3;
            v = *(const s16x8*)(xb + (size_t)tok * DIM + lane * 8);
        }
        int st = (p >> 4) & 1, m = p & 15;
        size_t off = ((((size_t)(G0 + (p >> 5)) * 16 + kt) * 2 + st) * 64
                      + (qq * 16 + m)) * 8;
        *(s16x8*)(xg + off) = v;
    }
}

// ---------------- K1: h = silu(X@W1)*(X@W3) -----------------------------------
// R0's register shape (16-col slices, acc=16, (256,3): VGPR 84, ZERO spill —
// proven WRITE=8.7MB) + R5's coalesced frag-ordered A from xg. The 32-col
// variants needed ~164 live regs: either spill (capped, R5/R8: 32MB scratch WR)
// or 1-block/CU occupancy (uncapped, R7) — both ~56-73us. This quadrant
// (no-spill AND 3 blocks/CU AND coalesced A) is the one never tested.
__global__ __launch_bounds__(256, 3) void gemm1_k(const short* __restrict__ xg,
                                                  const float* __restrict__ w1,
                                                  const float* __restrict__ w3,
                                                  const int* __restrict__ counts,
                                                  short* __restrict__ hgf)
{
    __shared__ short Bl[2][16][64][8];       // mat, kt, flane, j = 32 KB
    __shared__ short Ct[4][2][16][24];       // wave, sub, row, col(+pad) = 6 KB

    int e  = blockIdx.x & 63, cg = blockIdx.x >> 6;   // cg 0..15 -> 16-col slice
    int n0 = cg * 16;
    int tid = threadIdx.x;
    int w = tid >> 6, lane = tid & 63;
    int q = lane >> 4, m16 = lane & 15;

    int G0, ne, nt;
    tile_scan(counts, lane, e, G0, ne, nt);
    (void)ne;

    const float* W1e = w1 + (size_t)e * DIM * MOE + n0;
    const float* W3e = w3 + (size_t)e * DIM * MOE + n0;
#pragma unroll 4
    for (int it = 0; it < 8; ++it) {
        int idx = it * 256 + tid;
        int mat = idx >> 10;
        int rem = idx & 1023;
        int r2  = rem >> 2;              // row pair 0..255
        int cq  = (rem & 3) * 4;         // col 0,4,8,12
        int k   = r2 * 2;
        int kt = k >> 5, qf = (k >> 3) & 3, j0 = k & 7;
        const float* p = (mat ? W3e : W1e) + (size_t)k * MOE + cq;
        f32x4 lo = __builtin_nontemporal_load((const f32x4*)p);
        f32x4 hi = __builtin_nontemporal_load((const f32x4*)(p + MOE));
        unsigned* b = (unsigned*)&Bl[mat][kt][qf * 16 + cq][j0];
        b[0]  = pk2(lo.x, hi.x);
        b[4]  = pk2(lo.y, hi.y);
        b[8]  = pk2(lo.z, hi.z);
        b[12] = pk2(lo.w, hi.w);
    }
    __syncthreads();

    for (int T = w; T < nt; T += 4) {
        const short* A = xg + (size_t)(G0 + T) * 16384 + lane * 8;

        f32x4 acc[2][2];   // [sub][mat] = 16 regs
#pragma unroll
        for (int i = 0; i < 2; ++i)
#pragma unroll
            for (int j = 0; j < 2; ++j) acc[i][j] = (f32x4)0.f;

        // 2-deep rolling A-prefetch (static indices after unroll)
        s16x8 pa0[2], pa1[2];
#pragma unroll
        for (int i = 0; i < 2; ++i) {
            pa0[i] = *(const s16x8*)(A + (i * 2 + 0) * 512);
            pa1[i] = *(const s16x8*)(A + (i * 2 + 1) * 512);
        }
#pragma unroll
        for (int kt = 0; kt < 16; ++kt) {
            s16x8 a0 = pa0[kt & 1], a1 = pa1[kt & 1];
            if (kt < 14) {
                pa0[kt & 1] = *(const s16x8*)(A + ((kt + 2) * 2 + 0) * 512);
                pa1[kt & 1] = *(const s16x8*)(A + ((kt + 2) * 2 + 1) * 512);
            }
            s16x8 b1 = *(const s16x8*)&Bl[0][kt][lane][0];
            s16x8 b3 = *(const s16x8*)&Bl[1][kt][lane][0];
            acc[0][0] = __builtin_amdgcn_mfma_f32_16x16x32_bf16(a0, b1, acc[0][0], 0, 0, 0);
            acc[1][0] = __builtin_amdgcn_mfma_f32_16x16x32_bf16(a1, b1, acc[1][0], 0, 0, 0);
            acc[0][1] = __builtin_amdgcn_mfma_f32_16x16x32_bf16(a0, b3, acc[0][1], 0, 0, 0);
            acc[1][1] = __builtin_amdgcn_mfma_f32_16x16x32_bf16(a1, b3, acc[1][1], 0, 0, 0);
        }

        // epilogue: SwiGLU -> Ct (per-wave) -> contiguous frag store to hgf
        // (R0's verified mapping: col group c=cg: slot=(tile*8+(c>>1))*2+sub,
        //  in-slot ((c&1)*2+(q&1))*128 + m16*8 — matches gemm2's A-frag read)
#pragma unroll
        for (int sub = 0; sub < 2; ++sub)
#pragma unroll
            for (int r = 0; r < 4; ++r) {
                float g = acc[sub][0][r];
                float u = acc[sub][1][r];
                float hv = g / (1.f + __expf(-g)) * u;
                Ct[w][sub][q * 4 + r][m16] = (short)f2bf(hv);
            }
        int subr = q >> 1;
        s16x8 hv8 = *(const s16x8*)&Ct[w][subr][m16][(q & 1) * 8];
        size_t slot = ((size_t)(G0 + T) * 8 + (cg >> 1)) * 2 + subr;
        *(s16x8*)(hgf + slot * 512 + ((cg & 1) * 2 + (q & 1)) * 128 + m16 * 8) = hv8;
    }
}

// ---------------- K2: y = H@W2 ------------------------------------------------
// Same spill fix: 32-col slices (16 per expert, grid 1024), acc=16, (256,3)
// (the old 64-col acc=32 at the 84-reg cap was silently spilling all session).
// Depth-2 A-prefetch of linear L2-resident hgf, nt weight stage.
__global__ __launch_bounds__(256, 3) void gemm2_k(const short* __restrict__ hgf,
                                                  const float* __restrict__ w2,
                                                  const int* __restrict__ counts,
                                                  const int* __restrict__ etok,
                                                  short* __restrict__ ybuf)
{
    __shared__ short Bl[2][8][64][8];   // 16-col slice, kt2, flane, j = 16 KB

    int e  = blockIdx.x & 63, cg = blockIdx.x >> 6;   // cg 0..15 -> 32-col slice
    int n0 = cg * 32;
    int tid = threadIdx.x;
    int w = tid >> 6, lane = tid & 63;
    int q = lane >> 4, m16 = lane & 15;

    int G0, ne, nt;
    tile_scan(counts, lane, e, G0, ne, nt);

    const float* W2e = w2 + (size_t)e * MOE * DIM + n0;
#pragma unroll 4
    for (int it = 0; it < 4; ++it) {
        int idx = it * 256 + tid;
        int r2  = idx >> 3;              // row pair 0..127
        int cq  = (idx & 7) * 4;         // col 0..28 step 4
        int k   = r2 * 2;
        int kt2 = k >> 5, qf = (k >> 3) & 3, j0 = k & 7;
        int s = cq >> 4, c15 = cq & 15;
        const float* p = W2e + (size_t)k * DIM + cq;
        f32x4 lo = __builtin_nontemporal_load((const f32x4*)p);
        f32x4 hi = __builtin_nontemporal_load((const f32x4*)(p + DIM));
        unsigned* b = (unsigned*)&Bl[s][kt2][qf * 16 + c15][j0];
        b[0]  = pk2(lo.x, hi.x);
        b[4]  = pk2(lo.y, hi.y);
        b[8]  = pk2(lo.z, hi.z);
        b[12] = pk2(lo.w, hi.w);
    }
    __syncthreads();

    const int* el = etok + e * CAP;

    for (int T = w; T < nt; T += 4) {
        const short* A = hgf + (size_t)(G0 + T) * 8192 + lane * 8;

        int erid[2][4];                  // hoisted: issues el loads early
#pragma unroll
        for (int sub = 0; sub < 2; ++sub)
#pragma unroll
            for (int r = 0; r < 4; ++r) {
                int row = T * 32 + sub * 16 + q * 4 + r;
                erid[sub][r] = row < ne ? el[row] : -1;
            }

        f32x4 acc[2][2];   // [sub][slice] = 16 regs
#pragma unroll
        for (int i = 0; i < 2; ++i)
#pragma unroll
            for (int j = 0; j < 2; ++j) acc[i][j] = (f32x4)0.f;

        s16x8 pa0[2], pa1[2];
#pragma unroll
        for (int i = 0; i < 2; ++i) {
            pa0[i] = *(const s16x8*)(A + (i * 2 + 0) * 512);
            pa1[i] = *(const s16x8*)(A + (i * 2 + 1) * 512);
        }
#pragma unroll
        for (int kt = 0; kt < 8; ++kt) {
            s16x8 a0 = pa0[kt & 1], a1 = pa1[kt & 1];
            if (kt < 6) {
                pa0[kt & 1] = *(const s16x8*)(A + ((kt + 2) * 2 + 0) * 512);
                pa1[kt & 1] = *(const s16x8*)(A + ((kt + 2) * 2 + 1) * 512);
            }
            s16x8 b0 = *(const s16x8*)&Bl[0][kt][lane][0];
            s16x8 b1 = *(const s16x8*)&Bl[1][kt][lane][0];
            acc[0][0] = __builtin_amdgcn_mfma_f32_16x16x32_bf16(a0, b0, acc[0][0], 0, 0, 0);
            acc[1][0] = __builtin_amdgcn_mfma_f32_16x16x32_bf16(a1, b0, acc[1][0], 0, 0, 0);
            acc[0][1] = __builtin_amdgcn_mfma_f32_16x16x32_bf16(a0, b1, acc[0][1], 0, 0, 0);
            acc[1][1] = __builtin_amdgcn_mfma_f32_16x16x32_bf16(a1, b1, acc[1][1], 0, 0, 0);
        }

#pragma unroll
        for (int sub = 0; sub < 2; ++sub)
#pragma unroll
            for (int s = 0; s < 2; ++s)
#pragma unroll
                for (int r = 0; r < 4; ++r) {
                    if (erid[sub][r] >= 0)
                        ybuf[(size_t)erid[sub][r] * DIM + n0 + s * 16 + m16] =
                            (short)f2bf(acc[sub][s][r]);
                }
    }
}

// ---------------- Combine -----------------------------------------------------
__global__ __launch_bounds__(256) void combine_k(const short* __restrict__ ybuf,
                                                 const float* __restrict__ wt_of,
                                                 float* __restrict__ out)
{
    int t = blockIdx.x;
    int tid = threadIdx.x;
    const int* yb = (const int*)ybuf;
    float sx = 0.f, sy = 0.f;
#pragma unroll
    for (int k = 0; k < TOPK; ++k) {
        float wk = wt_of[t * TOPK + k];
        int v = yb[(size_t)(t * TOPK + k) * (DIM / 2) + tid];
        float lo = __builtin_bit_cast(float, (unsigned)v << 16);
        float hi = __builtin_bit_cast(float, (unsigned)v & 0xffff0000u);
        sx += wk * lo;
        sy += wk * hi;
    }
    float2 o = {sx, sy};
    ((float2*)out)[(size_t)t * (DIM / 2) + tid] = o;
}

extern "C" void kernel_launch(void* const* d_in, const int* in_sizes, int n_in,
                              void* d_out, int out_size, void* d_ws, size_t ws_size,
                              hipStream_t stream)
{
    const float* x  = (const float*)d_in[0];
    const float* gw = (const float*)d_in[1];
    const float* gb = (const float*)d_in[2];
    const float* w1 = (const float*)d_in[3];
    const float* w3 = (const float*)d_in[4];
    const float* w2 = (const float*)d_in[5];

    char* ws = (char*)d_ws;
    short* xb    = (short*)(ws);                      //  2,097,152
    short* hgf   = (short*)(ws + 2097152);            //  9,437,184
    short* xg    = (short*)(ws + 11534336);           // 18,874,368
    short* ybuf  = (short*)(ws + 11534336);           // 16,777,216 — ALIASES xg
                                                      // (xg dead after gemm1;
                                                      //  ybuf born in gemm2)
    float* gwT   = (float*)(ws + 30408704);           //    131,072
    int*   etok  = (int*)  (ws + 30539776);           //    262,144
    float* wt_of = (float*)(ws + 30801920);           //     65,536
    int*   counts= (int*)  (ws + 30867456);           //        256

    hipMemsetAsync(counts, 0, NE * 4, stream);

    gwt_k<<<128, 256, 0, stream>>>(gw, gwT);
    gate_fused_k<<<T_TOK / 4, 256, 0, stream>>>(x, gwT, gb, counts, etok, wt_of, xb);
    dispatch_k<<<NE * 8, 256, 0, stream>>>(xb, counts, etok, xg);
    gemm1_k<<<NE * 16, 256, 0, stream>>>(xg, w1, w3, counts, hgf);
    gemm2_k<<<NE * 16, 256, 0, stream>>>(hgf, w2, counts, etok, ybuf);
    combine_k<<<T_TOK, 256, 0, stream>>>(ybuf, wt_of, (float*)d_out);
}